// Round 3
// baseline (394.925 us; speedup 1.0000x reference)
//
#include <hip/hip_runtime.h>
#include <math.h>

#define N_NODES 50000
#define N_EDGES 400000
#define R_REL   35
#define B_BASES 12
#define C_DIM   128
#define HL_DIM  38
#define RI2     70            // R*2
#define NP      50304         // padded permuted node space (mult of 64)

// ---- ws float offsets ----
#define OFF_WT   0            // w[ri][c] = [70][128] = 8960
#define OFF_WQ   8960         // [70]
#define OFF_WK   9030         // [70]
#define OFF_LE   9100         // [2]
#define OFF_META 9104         // 12 ints: hist[4]@0, base_pad[4]@4, cursor[4]@8
#define OFF_PERM 9120         // int[50000]
#define OFF_INV  59120        // int[NP]
#define OFF_DEN  109424       // float[NP]  (16B aligned; contiguous with s_T)
#define OFF_S    159728       // float[70][NP]
#define ZERO_F4  ((71 * NP) / 4)   // 892,896 float4
#define ZERO_BLOCKS 3488           // ceil(892896/256)

// K1: zero den+s_T, zero hist, compute w[ri][c] = sum_b att_rel[r][b]*basis[b][i][c]
__global__ __launch_bounds__(256) void k_init(const float* __restrict__ basis,
                                              const float* __restrict__ att_rel,
                                              float* __restrict__ ws) {
    int b = blockIdx.x, tid = threadIdx.x;
    if (b < ZERO_BLOCKS) {
        int i = b * 256 + tid;
        if (i < ZERO_F4) ((float4*)(ws + OFF_DEN))[i] = make_float4(0.f, 0.f, 0.f, 0.f);
    } else if (b == ZERO_BLOCKS) {
        if (tid < 4) ((int*)(ws + OFF_META))[tid] = 0;
    } else {
        int idx = (b - (ZERO_BLOCKS + 1)) * 256 + tid;   // [0, 8960)
        if (idx < RI2 * C_DIM) {
            int c  = idx & (C_DIM - 1);
            int ri = idx >> 7;
            int r = ri >> 1, ii = ri & 1;
            float acc = 0.f;
            #pragma unroll
            for (int bb = 0; bb < B_BASES; ++bb)
                acc += att_rel[r * B_BASES + bb] * basis[(bb * 2 + ii) * C_DIM + c];
            ws[OFF_WT + idx] = acc;
        }
    }
}

// K2: type histogram
__global__ __launch_bounds__(256) void k_hist(const int* __restrict__ node_type,
                                              float* __restrict__ ws) {
    __shared__ int lh[4];
    int tid = threadIdx.x;
    if (tid < 4) lh[tid] = 0;
    __syncthreads();
    int i = blockIdx.x * 256 + tid;
    if (i < N_NODES) atomicAdd(&lh[node_type[i]], 1);
    __syncthreads();
    if (tid < 4 && lh[tid] > 0) atomicAdd(&((int*)(ws + OFF_META))[tid], lh[tid]);
}

// K3: wq/wk/le projections + 64-aligned scan of histogram
__global__ __launch_bounds__(256) void k_small(const float* __restrict__ q_att,
                                               const float* __restrict__ k_att,
                                               const float* __restrict__ e_att,
                                               const float* __restrict__ lin_edge_W,
                                               float* __restrict__ ws) {
    int tid = threadIdx.x;
    const float* w = ws + OFF_WT;
    if (tid < RI2) {
        float aq = 0.f, ak = 0.f;
        for (int c = 0; c < C_DIM; ++c) {
            float wv = w[tid * C_DIM + c];
            aq += wv * q_att[c];
            ak += wv * k_att[c];
        }
        ws[OFF_WQ + tid] = aq;
        ws[OFF_WK + tid] = ak;
    } else if (tid == 80 || tid == 81) {
        int j = tid - 80;
        float a = 0.f;
        for (int c = 0; c < C_DIM; ++c) a += lin_edge_W[j * C_DIM + c] * e_att[c];
        ws[OFF_LE + j] = a;
    } else if (tid == 200) {
        int* meta = (int*)(ws + OFF_META);
        int h0 = meta[0], h1 = meta[1], h2 = meta[2];
        int b1 = ((h0 + 63) >> 6) << 6;
        int b2 = b1 + (((h1 + 63) >> 6) << 6);
        int b3 = b2 + (((h2 + 63) >> 6) << 6);
        meta[4] = 0; meta[5] = b1; meta[6] = b2; meta[7] = b3;
        meta[8] = 0; meta[9] = 0; meta[10] = 0; meta[11] = 0;
    }
}

// K4: counting-sort scatter (wave-aggregated atomics)
__global__ __launch_bounds__(256) void k_perm(const int* __restrict__ node_type,
                                              float* __restrict__ ws) {
    int lane = threadIdx.x & 63;
    int n = blockIdx.x * 256 + threadIdx.x;
    int* meta = (int*)(ws + OFF_META);
    int* perm = (int*)(ws + OFF_PERM);
    int* inv  = (int*)(ws + OFF_INV);
    bool active = n < N_NODES;
    int ty = active ? node_type[n] : -1;
    for (int t = 0; t < 4; ++t) {
        bool mine = active && (ty == t);
        unsigned long long m = __ballot(mine);
        if (m == 0ULL) continue;
        int leader = __ffsll(m) - 1;
        int base = 0;
        if (lane == leader) base = atomicAdd(&meta[8 + t], __popcll(m));
        base = __shfl(base, leader);
        if (mine) {
            int p = meta[4 + t] + base + __popcll(m & ((1ULL << lane) - 1ULL));
            perm[n] = p;
            inv[p] = n;
        }
    }
}

// K5: edge pass -> 3 atomics into permuted space
__global__ __launch_bounds__(256) void k_edge(const float* __restrict__ x,
                                              const int* __restrict__ edge_index,
                                              const int* __restrict__ edge_type,
                                              const float* __restrict__ edge_attr,
                                              float* __restrict__ ws) {
    __shared__ float swq[RI2], swk[RI2], sle[2];
    int tid = threadIdx.x;
    if (tid < RI2) { swq[tid] = ws[OFF_WQ + tid]; swk[tid] = ws[OFF_WK + tid]; }
    if (tid < 2) sle[tid] = ws[OFF_LE + tid];
    __syncthreads();
    int e = blockIdx.x * 256 + tid;
    if (e >= N_EDGES) return;
    int src = edge_index[e];
    int dst = edge_index[N_EDGES + e];
    int r   = edge_type[e];
    int p   = ((const int*)(ws + OFF_PERM))[dst];
    float2 ea = *(const float2*)(edge_attr + 2 * e);
    float2 xs = *(const float2*)(x + 2 * src);
    float2 xd = *(const float2*)(x + 2 * dst);
    float alpha = xd.x * swq[2 * r] + xd.y * swq[2 * r + 1]
                + xs.x * swk[2 * r] + xs.y * swk[2 * r + 1]
                + ea.x * sle[0]     + ea.y * sle[1];
    alpha = alpha > 0.f ? alpha : 0.2f * alpha;
    float ex = __expf(alpha);
    atomicAdd(ws + OFF_DEN + p, ex);
    atomicAdd(ws + OFF_S + (2 * r) * NP + p,     ex * xs.x);
    atomicAdd(ws + OFF_S + (2 * r + 1) * NP + p, ex * xs.y);
}

// generic MLP layer slice: JN outputs starting at j0, K inputs from LDS (stride 64)
template<int JN, int K, bool RELU>
__device__ __forceinline__ void mlp_slice(const float* __restrict__ W,   // [K][38] row-major
                                          const float* __restrict__ bias, // [38]
                                          const float* srcL, float* dstL,
                                          int j0, int lane) {
    float y[JN];
    #pragma unroll
    for (int jj = 0; jj < JN; ++jj) y[jj] = bias[j0 + jj];
    for (int k = 0; k < K; ++k) {
        float v = srcL[k * 64 + lane];
        const float* wr = W + k * HL_DIM + j0;   // uniform -> s_load
        #pragma unroll
        for (int jj = 0; jj < JN; ++jj) y[jj] += v * wr[jj];
    }
    #pragma unroll
    for (int jj = 0; jj < JN; ++jj) {
        float v = y[jj];
        if (RELU) v = v > 0.f ? v : 0.f;
        dstL[(j0 + jj) * 64 + lane] = v;
    }
}

// K6: fused node pass — block = 64 nodes, 4 waves split c / j dimensions
__global__ __launch_bounds__(256) void k_node(
        const float* __restrict__ ws, const float* __restrict__ conv_bias,
        const float* __restrict__ lin0_W, const float* __restrict__ lin0_b,
        const float* __restrict__ lin1_W, const float* __restrict__ lin1_b,
        const float* __restrict__ lin2_W, const float* __restrict__ lin2_b,
        const float* __restrict__ fin_W,  const float* __restrict__ fin_b,
        float* __restrict__ out) {
    __shared__ float ldsH[C_DIM * 64];   // 32 KB
    __shared__ float ldsU[4864];         // s staging (4480) / yA(2432)+yB(2432)
    int tid = threadIdx.x;
    int lane = tid & 63;
    int wv   = tid >> 6;
    int p0 = blockIdx.x * 64;
    int p  = p0 + lane;

    // stage s tile [70][64] into LDS (coalesced)
    for (int idx = tid; idx < RI2 * 64; idx += 256) {
        int ri = idx >> 6, l = idx & 63;
        ldsU[idx] = ws[OFF_S + ri * NP + p0 + l];
    }

    const int* meta = (const int*)(ws + OFF_META);
    int b1 = __builtin_amdgcn_readfirstlane(meta[5]);
    int b2 = __builtin_amdgcn_readfirstlane(meta[6]);
    int b3 = __builtin_amdgcn_readfirstlane(meta[7]);
    int t  = (p0 >= b1) + (p0 >= b2) + (p0 >= b3);       // block-uniform
    int bp = __builtin_amdgcn_readfirstlane(meta[4 + t]);
    int cnt = __builtin_amdgcn_readfirstlane(meta[t]);
    bool valid = (p - bp) < cnt;
    int orig = valid ? ((const int*)(ws + OFF_INV))[p] : 0;
    float inv_dn = 1.0f / (ws[OFF_DEN + p] + 1e-16f);
    __syncthreads();

    // ---- phase 1: agg, wave w covers c in [32w, 32w+32)
    int c0 = wv * 32;
    float acc[32];
    #pragma unroll
    for (int cc = 0; cc < 32; ++cc) acc[cc] = 0.f;
    const float* wT = ws + OFF_WT;
    for (int ri = 0; ri < RI2; ++ri) {
        float sv = ldsU[ri * 64 + lane];
        const float* wr = wT + ri * C_DIM + c0;          // uniform -> s_load
        #pragma unroll
        for (int cc = 0; cc < 32; ++cc) acc[cc] += sv * wr[cc];
    }
    #pragma unroll
    for (int cc = 0; cc < 32; ++cc) {
        float hc = acc[cc] * inv_dn + conv_bias[c0 + cc];
        ldsH[(c0 + cc) * 64 + lane] = hc > 0.f ? hc : 0.f;   // relu(leaky(x))==relu(x)
    }
    __syncthreads();   // H ready; s region dead -> reuse as yA/yB

    float* yA = ldsU;
    float* yB = ldsU + HL_DIM * 64;
    int j0 = wv * 10;

    // ---- phase 2: lin0 [128]->[38], j split {10,10,10,8}
    {
        const float* W0 = lin0_W + t * C_DIM * HL_DIM;
        const float* b0 = lin0_b + t * HL_DIM;
        if (wv < 3) mlp_slice<10, C_DIM, true>(W0, b0, ldsH, yA, j0, lane);
        else        mlp_slice<8,  C_DIM, true>(W0, b0, ldsH, yA, j0, lane);
    }
    __syncthreads();
    // ---- phase 3: lin1 [38]->[38]
    {
        const float* W1 = lin1_W + t * HL_DIM * HL_DIM;
        const float* b1p = lin1_b + t * HL_DIM;
        if (wv < 3) mlp_slice<10, HL_DIM, true>(W1, b1p, yA, yB, j0, lane);
        else        mlp_slice<8,  HL_DIM, true>(W1, b1p, yA, yB, j0, lane);
    }
    __syncthreads();
    // ---- phase 4: lin2 [38]->[38], no relu
    {
        const float* W2 = lin2_W + t * HL_DIM * HL_DIM;
        const float* b2p = lin2_b + t * HL_DIM;
        if (wv < 3) mlp_slice<10, HL_DIM, false>(W2, b2p, yB, ldsH, j0, lane);
        else        mlp_slice<8,  HL_DIM, false>(W2, b2p, yB, ldsH, j0, lane);
    }
    __syncthreads();
    // ---- phase 5: fin [38]->[2] + type-0 abs, wave 0 only
    if (wv == 0 && valid) {
        const float* FW = fin_W + t * HL_DIM * 2;
        float o0 = fin_b[t * 2], o1 = fin_b[t * 2 + 1];
        for (int k = 0; k < HL_DIM; ++k) {
            float v = ldsH[k * 64 + lane];
            o0 += v * FW[k * 2];
            o1 += v * FW[k * 2 + 1];
        }
        if (t == 0) o1 = fabsf(o1);
        ((float2*)out)[orig] = make_float2(o0, o1);
    }
}

extern "C" void kernel_launch(void* const* d_in, const int* in_sizes, int n_in,
                              void* d_out, int out_size, void* d_ws, size_t ws_size,
                              hipStream_t stream) {
    const float* x          = (const float*)d_in[0];
    const int*   edge_index = (const int*)  d_in[1];
    const int*   edge_type  = (const int*)  d_in[2];
    const float* edge_attr  = (const float*)d_in[3];
    const int*   node_type  = (const int*)  d_in[4];
    const float* basis      = (const float*)d_in[5];
    const float* att_rel    = (const float*)d_in[6];
    const float* q_att      = (const float*)d_in[7];
    const float* k_att      = (const float*)d_in[8];
    const float* e_att      = (const float*)d_in[9];
    const float* lin_edge_W = (const float*)d_in[10];
    const float* conv_bias  = (const float*)d_in[11];
    const float* lin0_W     = (const float*)d_in[12];
    const float* lin0_b     = (const float*)d_in[13];
    const float* lin1_W     = (const float*)d_in[14];
    const float* lin1_b     = (const float*)d_in[15];
    const float* lin2_W     = (const float*)d_in[16];
    const float* lin2_b     = (const float*)d_in[17];
    const float* fin_W      = (const float*)d_in[18];
    const float* fin_b      = (const float*)d_in[19];

    float* ws  = (float*)d_ws;
    float* out = (float*)d_out;

    k_init <<<ZERO_BLOCKS + 1 + 35, 256, 0, stream>>>(basis, att_rel, ws);
    k_hist <<<(N_NODES + 255) / 256, 256, 0, stream>>>(node_type, ws);
    k_small<<<1, 256, 0, stream>>>(q_att, k_att, e_att, lin_edge_W, ws);
    k_perm <<<(N_NODES + 255) / 256, 256, 0, stream>>>(node_type, ws);
    k_edge <<<(N_EDGES + 255) / 256, 256, 0, stream>>>(x, edge_index, edge_type, edge_attr, ws);
    k_node <<<NP / 64, 256, 0, stream>>>(ws, conv_bias,
                                         lin0_W, lin0_b, lin1_W, lin1_b,
                                         lin2_W, lin2_b, fin_W, fin_b, out);
}

// Round 5
// 301.840 us; speedup vs baseline: 1.3084x; 1.3084x over previous
//
#include <hip/hip_runtime.h>
#include <math.h>

#define N_NODES 50000
#define N_EDGES 400000
#define R_REL   35
#define B_BASES 12
#define C_DIM   128
#define HL_DIM  38
#define RI2     70
#define NP      50304         // padded permuted node space (mult of 64)

// ---- ws float offsets ----
#define OFF_WT   0            // w[ri][c] = [70][128] = 8960
#define OFF_WQ   8960         // [70]
#define OFF_WK   9030         // [70]
#define OFF_LE   9100         // [2]
#define OFF_META 9104         // 12 ints
#define OFF_PERM 9120         // int[50000]
#define OFF_INV  59120        // int[NP]
#define OFF_DEN  109424       // float[NP]
#define OFF_S    159728       // float[NP][72] row-major
#define ZERO_F4  (NP * 73 / 4)     // den + s contiguous = 918,048 float4
#define ZERO_BLOCKS 3587

// ---- k_node LDS float offsets ----
#define CH    0        // k-chunk double buffer (2 x 1792)
#define ST    3584     // sT[70][68] = 4760 ; later y0T[<=64][68]
#define HH    8344     // H[128][64] = 8192 ; later y1T@HH, y2T@Y2T
#define Y2T   11608    // inside old H region; no live overlap (see comments)
#define SM_DINV 16536  // [64]
#define SM_CB   16600  // [128]
#define SM_B0   16728  // [38]
#define SM_B1   16766  // [38]
#define SM_B2   16804  // [38]
#define SM_FW   16844  // [76]
#define SM_FB   16920  // [2]
#define LDS_FLOATS 16928

// K1: zero den+s, zero hist, compute w[ri][c]
__global__ __launch_bounds__(256) void k_init(const float* __restrict__ basis,
                                              const float* __restrict__ att_rel,
                                              float* __restrict__ ws) {
    int b = blockIdx.x, tid = threadIdx.x;
    if (b < ZERO_BLOCKS) {
        int i = b * 256 + tid;
        if (i < ZERO_F4) ((float4*)(ws + OFF_DEN))[i] = make_float4(0.f, 0.f, 0.f, 0.f);
    } else if (b == ZERO_BLOCKS) {
        if (tid < 4) ((int*)(ws + OFF_META))[tid] = 0;
    } else {
        int idx = (b - (ZERO_BLOCKS + 1)) * 256 + tid;
        if (idx < RI2 * C_DIM) {
            int c  = idx & (C_DIM - 1);
            int ri = idx >> 7;
            int r = ri >> 1, ii = ri & 1;
            float acc = 0.f;
            #pragma unroll
            for (int bb = 0; bb < B_BASES; ++bb)
                acc += att_rel[r * B_BASES + bb] * basis[(bb * 2 + ii) * C_DIM + c];
            ws[OFF_WT + idx] = acc;
        }
    }
}

// K2: type histogram
__global__ __launch_bounds__(256) void k_hist(const int* __restrict__ node_type,
                                              float* __restrict__ ws) {
    __shared__ int lh[4];
    int tid = threadIdx.x;
    if (tid < 4) lh[tid] = 0;
    __syncthreads();
    int i = blockIdx.x * 256 + tid;
    if (i < N_NODES) atomicAdd(&lh[node_type[i]], 1);
    __syncthreads();
    if (tid < 4 && lh[tid] > 0) atomicAdd(&((int*)(ws + OFF_META))[tid], lh[tid]);
}

// K3: wq/wk/le projections + 64-aligned scan
__global__ __launch_bounds__(256) void k_small(const float* __restrict__ q_att,
                                               const float* __restrict__ k_att,
                                               const float* __restrict__ e_att,
                                               const float* __restrict__ lin_edge_W,
                                               float* __restrict__ ws) {
    int tid = threadIdx.x;
    const float* w = ws + OFF_WT;
    if (tid < RI2) {
        float aq = 0.f, ak = 0.f;
        for (int c = 0; c < C_DIM; ++c) {
            float wv = w[tid * C_DIM + c];
            aq += wv * q_att[c];
            ak += wv * k_att[c];
        }
        ws[OFF_WQ + tid] = aq;
        ws[OFF_WK + tid] = ak;
    } else if (tid == 80 || tid == 81) {
        int j = tid - 80;
        float a = 0.f;
        for (int c = 0; c < C_DIM; ++c) a += lin_edge_W[j * C_DIM + c] * e_att[c];
        ws[OFF_LE + j] = a;
    } else if (tid == 200) {
        int* meta = (int*)(ws + OFF_META);
        int h0 = meta[0], h1 = meta[1], h2 = meta[2];
        int b1 = ((h0 + 63) >> 6) << 6;
        int b2 = b1 + (((h1 + 63) >> 6) << 6);
        int b3 = b2 + (((h2 + 63) >> 6) << 6);
        meta[4] = 0; meta[5] = b1; meta[6] = b2; meta[7] = b3;
        meta[8] = 0; meta[9] = 0; meta[10] = 0; meta[11] = 0;
    }
}

// K4: counting-sort scatter
__global__ __launch_bounds__(256) void k_perm(const int* __restrict__ node_type,
                                              float* __restrict__ ws) {
    int lane = threadIdx.x & 63;
    int n = blockIdx.x * 256 + threadIdx.x;
    int* meta = (int*)(ws + OFF_META);
    int* perm = (int*)(ws + OFF_PERM);
    int* inv  = (int*)(ws + OFF_INV);
    bool active = n < N_NODES;
    int ty = active ? node_type[n] : -1;
    for (int t = 0; t < 4; ++t) {
        bool mine = active && (ty == t);
        unsigned long long m = __ballot(mine);
        if (m == 0ULL) continue;
        int leader = __ffsll(m) - 1;
        int base = 0;
        if (lane == leader) base = atomicAdd(&meta[8 + t], __popcll(m));
        base = __shfl(base, leader);
        if (mine) {
            int p = meta[4 + t] + base + __popcll(m & ((1ULL << lane) - 1ULL));
            perm[n] = p;
            inv[p] = n;
        }
    }
}

// K5: edge pass -> x/y atomics share a cache line (row-major s), den hot per node
__global__ __launch_bounds__(256) void k_edge(const float* __restrict__ x,
                                              const int* __restrict__ edge_index,
                                              const int* __restrict__ edge_type,
                                              const float* __restrict__ edge_attr,
                                              float* __restrict__ ws) {
    __shared__ float swq[RI2], swk[RI2], sle[2];
    int tid = threadIdx.x;
    if (tid < RI2) { swq[tid] = ws[OFF_WQ + tid]; swk[tid] = ws[OFF_WK + tid]; }
    if (tid < 2) sle[tid] = ws[OFF_LE + tid];
    __syncthreads();
    int e = blockIdx.x * 256 + tid;
    if (e >= N_EDGES) return;
    int src = edge_index[e];
    int dst = edge_index[N_EDGES + e];
    int r   = edge_type[e];
    int p   = ((const int*)(ws + OFF_PERM))[dst];
    float2 ea = *(const float2*)(edge_attr + 2 * e);
    float2 xs = *(const float2*)(x + 2 * src);
    float2 xd = *(const float2*)(x + 2 * dst);
    float alpha = xd.x * swq[2 * r] + xd.y * swq[2 * r + 1]
                + xs.x * swk[2 * r] + xs.y * swk[2 * r + 1]
                + ea.x * sle[0]     + ea.y * sle[1];
    alpha = alpha > 0.f ? alpha : 0.2f * alpha;
    float ex = __expf(alpha);
    float* srow = ws + OFF_S + (size_t)p * 72 + 2 * r;
    atomicAdd(srow,     ex * xs.x);
    atomicAdd(srow + 1, ex * xs.y);
    atomicAdd(ws + OFF_DEN + p, ex);
}

// K6: fused node pass — 64 nodes/block, register-tiled GEMM chain, DS-only inner loops
__global__ __launch_bounds__(256) void k_node(
        const float* __restrict__ ws, const float* __restrict__ conv_bias,
        const float* __restrict__ lin0_W, const float* __restrict__ lin0_b,
        const float* __restrict__ lin1_W, const float* __restrict__ lin1_b,
        const float* __restrict__ lin2_W, const float* __restrict__ lin2_b,
        const float* __restrict__ fin_W,  const float* __restrict__ fin_b,
        float* __restrict__ out) {
    __shared__ float L[LDS_FLOATS];
    int tid  = threadIdx.x;
    int lane = tid & 63;
    int wv   = tid >> 6;
    int p0   = blockIdx.x * 64;

    const int* meta = (const int*)(ws + OFF_META);
    int b1 = meta[5], b2 = meta[6], b3 = meta[7];
    int t  = (p0 >= b1) + (p0 >= b2) + (p0 >= b3);   // block-uniform (bases 64-aligned)
    int bp = meta[4 + t];
    int cnt = meta[t];

    // ---------- stage A: sT (transposed), dinv, small consts, wT chunk 0
    const float* sG = ws + OFF_S + (size_t)p0 * 72;
    for (int idx4 = tid; idx4 < 1152; idx4 += 256) {    // 64 rows x 18 float4
        float4 v = ((const float4*)sG)[idx4];
        int e = idx4 * 4;
        int n = e / 72;
        int k = e - n * 72;          // multiple of 4
        if (k < 68) {
            L[ST + (k + 0) * 68 + n] = v.x;
            L[ST + (k + 1) * 68 + n] = v.y;
            L[ST + (k + 2) * 68 + n] = v.z;
            L[ST + (k + 3) * 68 + n] = v.w;
        } else {                     // k == 68: slots 70,71 are pad
            L[ST + 68 * 68 + n] = v.x;
            L[ST + 69 * 68 + n] = v.y;
        }
    }
    if (tid < 64)
        L[SM_DINV + tid] = 1.0f / (ws[OFF_DEN + p0 + tid] + 1e-16f);
    if (tid < 128) L[SM_CB + tid] = conv_bias[tid];
    if (tid >= 64 && tid < 256) {    // exactly 192 small slots
        int i = tid - 64;
        if      (i < 38)  L[SM_B0 + i]        = lin0_b[t * HL_DIM + i];
        else if (i < 76)  L[SM_B1 + i - 38]   = lin1_b[t * HL_DIM + i - 38];
        else if (i < 114) L[SM_B2 + i - 76]   = lin2_b[t * HL_DIM + i - 76];
        else if (i < 190) L[SM_FW + i - 114]  = fin_W[t * 76 + i - 114];
        else              L[SM_FB + i - 190]  = fin_b[t * 2 + i - 190];
    }
    const float* wT_g = ws + OFF_WT;
    // wT chunk 0: [14][128] = 448 float4 — STRIDED over 256 threads (fixes R4 bug)
    for (int i4 = tid; i4 < 448; i4 += 256) {
        float4 v = ((const float4*)wT_g)[i4];
        *(float4*)&L[CH + i4 * 4] = v;   // contiguous layout == [row][128]
    }
    __syncthreads();

    // ---------- GEMM1: H[64n x 128c] = sT x wT ; wave c-slice 32, lane 4n x 8c
    int ng = lane & 15, cg = lane >> 4;
    int c0 = wv * 32 + cg * 8;
    float acc[32];
    #pragma unroll
    for (int i = 0; i < 32; ++i) acc[i] = 0.f;
    int cur = 0;
    for (int q = 0; q < 5; ++q) {
        // register prefetch of chunk q+1 (448 float4 over 256 threads: 2/thread)
        float4 pf0, pf1;
        if (q < 4) {
            const float4* src = (const float4*)(wT_g + (q + 1) * 1792);
            pf0 = src[tid];
            if (tid < 192) pf1 = src[tid + 256];
        }
        const float* wb = &L[CH + cur * 1792];
        #pragma unroll
        for (int kk = 0; kk < 14; ++kk) {
            float4 a4 = *(const float4*)&L[ST + (q * 14 + kk) * 68 + ng * 4];
            float4 wa = *(const float4*)&wb[kk * 128 + c0];
            float4 wc = *(const float4*)&wb[kk * 128 + c0 + 4];
            float a_[4] = {a4.x, a4.y, a4.z, a4.w};
            float w_[8] = {wa.x, wa.y, wa.z, wa.w, wc.x, wc.y, wc.z, wc.w};
            #pragma unroll
            for (int ni = 0; ni < 4; ++ni)
                #pragma unroll
                for (int ci = 0; ci < 8; ++ci)
                    acc[ni * 8 + ci] += a_[ni] * w_[ci];
        }
        if (q < 4) {
            float* dstb = &L[CH + (cur ^ 1) * 1792];
            *(float4*)&dstb[tid * 4] = pf0;
            if (tid < 192) *(float4*)&dstb[(tid + 256) * 4] = pf1;
        }
        cur ^= 1;
        __syncthreads();
    }

    // epilogue 1: h = relu(acc*dinv + cb) -> H[c][n]
    {
        float4 dv = *(const float4*)&L[SM_DINV + ng * 4];
        float d_[4] = {dv.x, dv.y, dv.z, dv.w};
        #pragma unroll
        for (int ci = 0; ci < 8; ++ci) {
            float cb = L[SM_CB + c0 + ci];
            float4 hv;
            float h0 = acc[0 * 8 + ci] * d_[0] + cb;
            float h1 = acc[1 * 8 + ci] * d_[1] + cb;
            float h2 = acc[2 * 8 + ci] * d_[2] + cb;
            float h3 = acc[3 * 8 + ci] * d_[3] + cb;
            hv.x = h0 > 0.f ? h0 : 0.f;
            hv.y = h1 > 0.f ? h1 : 0.f;
            hv.z = h2 > 0.f ? h2 : 0.f;
            hv.w = h3 > 0.f ? h3 : 0.f;
            *(float4*)&L[HH + (c0 + ci) * 64 + ng * 4] = hv;
        }
    }
    const float* W0g = lin0_W + t * C_DIM * HL_DIM;
    // W0 chunk 0: rows 0..15 -> [16][40] — STRIDED (fixes R4 bug)
    for (int i = tid; i < 608; i += 256) {
        int cc = i / 38, j = i - cc * 38;
        L[CH + cc * 40 + j] = W0g[i];
    }
    __syncthreads();

    // ---------- GEMM2: y0[64n x 48j] = H x W0 ; lane 4n x 4j
    int jg = lane >> 4;
    int j0 = wv * 16 + jg * 4;
    float acc2[16];
    #pragma unroll
    for (int i = 0; i < 16; ++i) acc2[i] = 0.f;
    int cur2 = 0;
    for (int q = 0; q < 8; ++q) {
        // register prefetch of chunk q+1 (608 floats over 256 threads: <=3/thread)
        float pa, pb, pc;
        if (q < 7) {
            const float* src = W0g + (q + 1) * 608;
            pa = src[tid];
            if (tid < 608 - 256) pb = src[tid + 256];
            if (tid < 608 - 512) pc = src[tid + 512];
        }
        const float* wb = &L[CH + cur2 * 1792];
        #pragma unroll
        for (int kk = 0; kk < 16; ++kk) {
            int c = q * 16 + kk;
            float4 a4 = *(const float4*)&L[HH + c * 64 + ng * 4];
            float4 w4 = *(const float4*)&wb[kk * 40 + j0];
            float a_[4] = {a4.x, a4.y, a4.z, a4.w};
            float w_[4] = {w4.x, w4.y, w4.z, w4.w};
            #pragma unroll
            for (int ni = 0; ni < 4; ++ni)
                #pragma unroll
                for (int ji = 0; ji < 4; ++ji)
                    acc2[ni * 4 + ji] += a_[ni] * w_[ji];
        }
        if (q < 7) {
            float* dstb = &L[CH + (cur2 ^ 1) * 1792];
            int i = tid, cc = i / 38, j = i - cc * 38;
            dstb[cc * 40 + j] = pa;
            if (tid < 608 - 256) { i = tid + 256; cc = i / 38; j = i - cc * 38; dstb[cc * 40 + j] = pb; }
            if (tid < 608 - 512) { i = tid + 512; cc = i / 38; j = i - cc * 38; dstb[cc * 40 + j] = pc; }
        }
        cur2 ^= 1;
        __syncthreads();
    }
    // epilogue 2: relu(y0 + b0) -> y0T[j][n] (rows j>=38 garbage, never read)
    #pragma unroll
    for (int ji = 0; ji < 4; ++ji) {
        int j = j0 + ji;
        float b = (j < 38) ? L[SM_B0 + j] : 0.f;
        float4 yv;
        float y0 = acc2[0 * 4 + ji] + b;
        float y1 = acc2[1 * 4 + ji] + b;
        float y2 = acc2[2 * 4 + ji] + b;
        float y3 = acc2[3 * 4 + ji] + b;
        yv.x = y0 > 0.f ? y0 : 0.f;
        yv.y = y1 > 0.f ? y1 : 0.f;
        yv.z = y2 > 0.f ? y2 : 0.f;
        yv.w = y3 > 0.f ? y3 : 0.f;
        *(float4*)&L[ST + j * 68 + ng * 4] = yv;   // y0T reuses sT region
    }
    // stage W1/W2: [38][40] each (this loop was already correct in R4)
    {
        const float* W1g = lin1_W + t * HL_DIM * HL_DIM;
        const float* W2g = lin2_W + t * HL_DIM * HL_DIM;
        for (int i = tid; i < 1444; i += 256) {
            int cc = i / 38, j = i - cc * 38;
            L[CH + cc * 40 + j] = W1g[i];
            L[CH + 1520 + cc * 40 + j] = W2g[i];
        }
    }
    __syncthreads();

    // ---------- GEMM3: y1 = y0 x W1 (k=38, fully resident)
    float acc3[16];
    #pragma unroll
    for (int i = 0; i < 16; ++i) acc3[i] = 0.f;
    #pragma unroll 2
    for (int kk = 0; kk < 38; ++kk) {
        float4 a4 = *(const float4*)&L[ST + kk * 68 + ng * 4];
        float4 w4 = *(const float4*)&L[CH + kk * 40 + j0];
        float a_[4] = {a4.x, a4.y, a4.z, a4.w};
        float w_[4] = {w4.x, w4.y, w4.z, w4.w};
        #pragma unroll
        for (int ni = 0; ni < 4; ++ni)
            #pragma unroll
            for (int ji = 0; ji < 4; ++ji)
                acc3[ni * 4 + ji] += a_[ni] * w_[ji];
    }
    __syncthreads();
    #pragma unroll
    for (int ji = 0; ji < 4; ++ji) {
        int j = j0 + ji;
        float b = (j < 38) ? L[SM_B1 + j] : 0.f;
        float4 yv;
        float y0 = acc3[0 * 4 + ji] + b;
        float y1 = acc3[1 * 4 + ji] + b;
        float y2 = acc3[2 * 4 + ji] + b;
        float y3 = acc3[3 * 4 + ji] + b;
        yv.x = y0 > 0.f ? y0 : 0.f;
        yv.y = y1 > 0.f ? y1 : 0.f;
        yv.z = y2 > 0.f ? y2 : 0.f;
        yv.w = y3 > 0.f ? y3 : 0.f;
        *(float4*)&L[HH + j * 68 + ng * 4] = yv;   // y1T in (dead) H region
    }
    __syncthreads();

    // ---------- GEMM4: y2 = y1 x W2 (no relu on output)
    float acc4[16];
    #pragma unroll
    for (int i = 0; i < 16; ++i) acc4[i] = 0.f;
    #pragma unroll 2
    for (int kk = 0; kk < 38; ++kk) {
        float4 a4 = *(const float4*)&L[HH + kk * 68 + ng * 4];
        float4 w4 = *(const float4*)&L[CH + 1520 + kk * 40 + j0];
        float a_[4] = {a4.x, a4.y, a4.z, a4.w};
        float w_[4] = {w4.x, w4.y, w4.z, w4.w};
        #pragma unroll
        for (int ni = 0; ni < 4; ++ni)
            #pragma unroll
            for (int ji = 0; ji < 4; ++ji)
                acc4[ni * 4 + ji] += a_[ni] * w_[ji];
    }
    // y2T writes land at HH+3264.. ; GEMM4 reads only HH+[0,2584) — disjoint, safe pre-sync
    #pragma unroll
    for (int ji = 0; ji < 4; ++ji) {
        int j = j0 + ji;
        float b = (j < 38) ? L[SM_B2 + j] : 0.f;
        float4 yv;
        yv.x = acc4[0 * 4 + ji] + b;
        yv.y = acc4[1 * 4 + ji] + b;
        yv.z = acc4[2 * 4 + ji] + b;
        yv.w = acc4[3 * 4 + ji] + b;
        *(float4*)&L[Y2T + j * 68 + ng * 4] = yv;
    }
    __syncthreads();

    // ---------- final: fin [38]->[2], thread-per-node
    if (tid < 64) {
        int p = p0 + tid;
        bool valid = (p - bp) < cnt;
        float o0 = L[SM_FB], o1 = L[SM_FB + 1];
        for (int jj = 0; jj < 38; ++jj) {
            float v = L[Y2T + jj * 68 + tid];
            float2 f = *(const float2*)&L[SM_FW + jj * 2];
            o0 += v * f.x;
            o1 += v * f.y;
        }
        if (t == 0) o1 = fabsf(o1);
        if (valid) {
            int orig = ((const int*)(ws + OFF_INV))[p];
            ((float2*)out)[orig] = make_float2(o0, o1);
        }
    }
}

extern "C" void kernel_launch(void* const* d_in, const int* in_sizes, int n_in,
                              void* d_out, int out_size, void* d_ws, size_t ws_size,
                              hipStream_t stream) {
    const float* x          = (const float*)d_in[0];
    const int*   edge_index = (const int*)  d_in[1];
    const int*   edge_type  = (const int*)  d_in[2];
    const float* edge_attr  = (const float*)d_in[3];
    const int*   node_type  = (const int*)  d_in[4];
    const float* basis      = (const float*)d_in[5];
    const float* att_rel    = (const float*)d_in[6];
    const float* q_att      = (const float*)d_in[7];
    const float* k_att      = (const float*)d_in[8];
    const float* e_att      = (const float*)d_in[9];
    const float* lin_edge_W = (const float*)d_in[10];
    const float* conv_bias  = (const float*)d_in[11];
    const float* lin0_W     = (const float*)d_in[12];
    const float* lin0_b     = (const float*)d_in[13];
    const float* lin1_W     = (const float*)d_in[14];
    const float* lin1_b     = (const float*)d_in[15];
    const float* lin2_W     = (const float*)d_in[16];
    const float* lin2_b     = (const float*)d_in[17];
    const float* fin_W      = (const float*)d_in[18];
    const float* fin_b      = (const float*)d_in[19];

    float* ws  = (float*)d_ws;
    float* out = (float*)d_out;

    k_init <<<ZERO_BLOCKS + 1 + 35, 256, 0, stream>>>(basis, att_rel, ws);
    k_hist <<<(N_NODES + 255) / 256, 256, 0, stream>>>(node_type, ws);
    k_small<<<1, 256, 0, stream>>>(q_att, k_att, e_att, lin_edge_W, ws);
    k_perm <<<(N_NODES + 255) / 256, 256, 0, stream>>>(node_type, ws);
    k_edge <<<(N_EDGES + 255) / 256, 256, 0, stream>>>(x, edge_index, edge_type, edge_attr, ws);
    k_node <<<NP / 64, 256, 0, stream>>>(ws, conv_bias,
                                         lin0_W, lin0_b, lin1_W, lin1_b,
                                         lin2_W, lin2_b, fin_W, fin_b, out);
}

// Round 6
// 229.209 us; speedup vs baseline: 1.7230x; 1.3169x over previous
//
#include <hip/hip_runtime.h>
#include <math.h>

#define N_NODES 50000
#define N_EDGES 400000
#define R_REL   35
#define B_BASES 12
#define C_DIM   128
#define HL_DIM  38
#define RI2     70
#define NP      50304         // padded permuted node space (mult of 64)
#define NB_HIST 196           // ceil(50000/256)

// ---- ws float offsets ----
#define OFF_WT    0           // w[ri][c] = [70][128] = 8960
#define OFF_WQ    8960        // [70]
#define OFF_WK    9030        // [70]
#define OFF_LE    9100        // [2]
#define OFF_META  9104        // 16 ints: counts[4]@0, base_pad[4]@4
#define OFF_HBLK  9120        // int[196][4] per-block type histogram
#define OFF_BBASE 9904        // int[196][4] per-block per-type dest base
#define OFF_PERM  10688       // int[50000]
#define OFF_INV   60688       // int[NP]
#define OFF_DEN   110992      // float[NP]
#define OFF_S     161296      // float[NP][72] row-major
#define ZERO_F4   (NP * 73 / 4)    // den + s contiguous = 918,048 float4
#define ZERO_BLOCKS 3587

// ---- k_node LDS float offsets (unchanged from R5) ----
#define CH    0
#define ST    3584
#define HH    8344
#define Y2T   11608
#define SM_DINV 16536
#define SM_CB   16600
#define SM_B0   16728
#define SM_B1   16766
#define SM_B2   16804
#define SM_FW   16844
#define SM_FB   16920
#define LDS_FLOATS 16928

// K1: zero den+s, compute w[ri][c]
__global__ __launch_bounds__(256) void k_init(const float* __restrict__ basis,
                                              const float* __restrict__ att_rel,
                                              float* __restrict__ ws) {
    int b = blockIdx.x, tid = threadIdx.x;
    if (b < ZERO_BLOCKS) {
        int i = b * 256 + tid;
        if (i < ZERO_F4) ((float4*)(ws + OFF_DEN))[i] = make_float4(0.f, 0.f, 0.f, 0.f);
    } else {
        int idx = (b - ZERO_BLOCKS) * 256 + tid;
        if (idx < RI2 * C_DIM) {
            int c  = idx & (C_DIM - 1);
            int ri = idx >> 7;
            int r = ri >> 1, ii = ri & 1;
            float acc = 0.f;
            #pragma unroll
            for (int bb = 0; bb < B_BASES; ++bb)
                acc += att_rel[r * B_BASES + bb] * basis[(bb * 2 + ii) * C_DIM + c];
            ws[OFF_WT + idx] = acc;
        }
    }
}

// K2: per-block type histogram (no global atomics)
__global__ __launch_bounds__(256) void k_histblk(const int* __restrict__ node_type,
                                                 float* __restrict__ ws) {
    __shared__ int lh[4];
    int tid = threadIdx.x;
    if (tid < 4) lh[tid] = 0;
    __syncthreads();
    int i = blockIdx.x * 256 + tid;
    if (i < N_NODES) atomicAdd(&lh[node_type[i]], 1);
    __syncthreads();
    if (tid < 4) ((int*)(ws + OFF_HBLK))[blockIdx.x * 4 + tid] = lh[tid];
}

// K3: scan per-block histograms -> per-block bases + meta (1 tiny block)
__global__ __launch_bounds__(256) void k_scan(float* __restrict__ ws) {
    __shared__ int lh[NB_HIST * 4];
    __shared__ int basel[4], tot[4];
    int tid = threadIdx.x;
    const int* hblk = (const int*)(ws + OFF_HBLK);
    for (int i = tid; i < NB_HIST * 4; i += 256) lh[i] = hblk[i];
    __syncthreads();
    if (tid < 4) {
        int run = 0;
        for (int b = 0; b < NB_HIST; ++b) {
            int v = lh[b * 4 + tid];
            lh[b * 4 + tid] = run;
            run += v;
        }
        tot[tid] = run;
    }
    __syncthreads();
    if (tid == 0) {
        int* meta = (int*)(ws + OFF_META);
        int t0 = tot[0], t1 = tot[1], t2 = tot[2], t3 = tot[3];
        int b1 = ((t0 + 63) >> 6) << 6;
        int b2 = b1 + (((t1 + 63) >> 6) << 6);
        int b3 = b2 + (((t2 + 63) >> 6) << 6);
        meta[0] = t0; meta[1] = t1; meta[2] = t2; meta[3] = t3;
        meta[4] = 0;  meta[5] = b1; meta[6] = b2; meta[7] = b3;
        basel[0] = 0; basel[1] = b1; basel[2] = b2; basel[3] = b3;
    }
    __syncthreads();
    int* bbase = (int*)(ws + OFF_BBASE);
    for (int i = tid; i < NB_HIST * 4; i += 256) bbase[i] = basel[i & 3] + lh[i];
}

// K4: wq/wk/le projections — one wave each, parallel (replaces serial 1-block k_small)
__global__ __launch_bounds__(64) void k_proj(const float* __restrict__ q_att,
                                             const float* __restrict__ k_att,
                                             const float* __restrict__ e_att,
                                             const float* __restrict__ lin_edge_W,
                                             float* __restrict__ ws) {
    int b = blockIdx.x, l = threadIdx.x;
    if (b < RI2) {
        const float* wr = ws + OFF_WT + b * C_DIM;
        float w1 = wr[l], w2 = wr[64 + l];
        float aq = w1 * q_att[l] + w2 * q_att[64 + l];
        float ak = w1 * k_att[l] + w2 * k_att[64 + l];
        #pragma unroll
        for (int off = 32; off; off >>= 1) {
            aq += __shfl_xor(aq, off, 64);
            ak += __shfl_xor(ak, off, 64);
        }
        if (l == 0) { ws[OFF_WQ + b] = aq; ws[OFF_WK + b] = ak; }
    } else {
        int j = b - RI2;
        const float* er = lin_edge_W + j * C_DIM;
        float a = er[l] * e_att[l] + er[64 + l] * e_att[64 + l];
        #pragma unroll
        for (int off = 32; off; off >>= 1) a += __shfl_xor(a, off, 64);
        if (l == 0) ws[OFF_LE + j] = a;
    }
}

// K5: permutation — ballots + LDS partials, ZERO atomics, deterministic
__global__ __launch_bounds__(256) void k_perm(const int* __restrict__ node_type,
                                              float* __restrict__ ws) {
    __shared__ int wcnt[4][4];
    int tid = threadIdx.x;
    int lane = tid & 63, wv = tid >> 6;
    int n = blockIdx.x * 256 + tid;
    bool active = n < N_NODES;
    int ty = active ? node_type[n] : -1;
    int myrank = 0;
    #pragma unroll
    for (int t = 0; t < 4; ++t) {
        unsigned long long m = __ballot(ty == t);
        if (lane == 0) wcnt[wv][t] = __popcll(m);
        if (ty == t) myrank = __popcll(m & ((1ULL << lane) - 1ULL));
    }
    __syncthreads();
    if (active) {
        int pre = 0;
        for (int w2 = 0; w2 < wv; ++w2) pre += wcnt[w2][ty];
        int p = ((const int*)(ws + OFF_BBASE))[blockIdx.x * 4 + ty] + pre + myrank;
        ((int*)(ws + OFF_PERM))[n] = p;
        ((int*)(ws + OFF_INV))[p] = n;
    }
}

// K6: edge pass -> 3 atomics (x/y share a cache line)
__global__ __launch_bounds__(256) void k_edge(const float* __restrict__ x,
                                              const int* __restrict__ edge_index,
                                              const int* __restrict__ edge_type,
                                              const float* __restrict__ edge_attr,
                                              float* __restrict__ ws) {
    __shared__ float swq[RI2], swk[RI2], sle[2];
    int tid = threadIdx.x;
    if (tid < RI2) { swq[tid] = ws[OFF_WQ + tid]; swk[tid] = ws[OFF_WK + tid]; }
    if (tid < 2) sle[tid] = ws[OFF_LE + tid];
    __syncthreads();
    int e = blockIdx.x * 256 + tid;
    if (e >= N_EDGES) return;
    int src = edge_index[e];
    int dst = edge_index[N_EDGES + e];
    int r   = edge_type[e];
    int p   = ((const int*)(ws + OFF_PERM))[dst];
    float2 ea = *(const float2*)(edge_attr + 2 * e);
    float2 xs = *(const float2*)(x + 2 * src);
    float2 xd = *(const float2*)(x + 2 * dst);
    float alpha = xd.x * swq[2 * r] + xd.y * swq[2 * r + 1]
                + xs.x * swk[2 * r] + xs.y * swk[2 * r + 1]
                + ea.x * sle[0]     + ea.y * sle[1];
    alpha = alpha > 0.f ? alpha : 0.2f * alpha;
    float ex = __expf(alpha);
    float* srow = ws + OFF_S + (size_t)p * 72 + 2 * r;
    atomicAdd(srow,     ex * xs.x);
    atomicAdd(srow + 1, ex * xs.y);
    atomicAdd(ws + OFF_DEN + p, ex);
}

// K7: fused node pass — 64 nodes/block, register-tiled GEMM chain (unchanged logic)
__global__ __launch_bounds__(256) void k_node(
        const float* __restrict__ ws, const float* __restrict__ conv_bias,
        const float* __restrict__ lin0_W, const float* __restrict__ lin0_b,
        const float* __restrict__ lin1_W, const float* __restrict__ lin1_b,
        const float* __restrict__ lin2_W, const float* __restrict__ lin2_b,
        const float* __restrict__ fin_W,  const float* __restrict__ fin_b,
        float* __restrict__ out) {
    __shared__ float L[LDS_FLOATS];
    int tid  = threadIdx.x;
    int lane = tid & 63;
    int wv   = tid >> 6;
    int p0   = blockIdx.x * 64;

    const int* meta = (const int*)(ws + OFF_META);
    int b1 = meta[5], b2 = meta[6], b3 = meta[7];
    int t  = (p0 >= b1) + (p0 >= b2) + (p0 >= b3);
    int bp = meta[4 + t];
    int cnt = meta[t];

    const float* sG = ws + OFF_S + (size_t)p0 * 72;
    for (int idx4 = tid; idx4 < 1152; idx4 += 256) {
        float4 v = ((const float4*)sG)[idx4];
        int e = idx4 * 4;
        int n = e / 72;
        int k = e - n * 72;
        if (k < 68) {
            L[ST + (k + 0) * 68 + n] = v.x;
            L[ST + (k + 1) * 68 + n] = v.y;
            L[ST + (k + 2) * 68 + n] = v.z;
            L[ST + (k + 3) * 68 + n] = v.w;
        } else {
            L[ST + 68 * 68 + n] = v.x;
            L[ST + 69 * 68 + n] = v.y;
        }
    }
    if (tid < 64)
        L[SM_DINV + tid] = 1.0f / (ws[OFF_DEN + p0 + tid] + 1e-16f);
    if (tid < 128) L[SM_CB + tid] = conv_bias[tid];
    if (tid >= 64 && tid < 256) {
        int i = tid - 64;
        if      (i < 38)  L[SM_B0 + i]        = lin0_b[t * HL_DIM + i];
        else if (i < 76)  L[SM_B1 + i - 38]   = lin1_b[t * HL_DIM + i - 38];
        else if (i < 114) L[SM_B2 + i - 76]   = lin2_b[t * HL_DIM + i - 76];
        else if (i < 190) L[SM_FW + i - 114]  = fin_W[t * 76 + i - 114];
        else              L[SM_FB + i - 190]  = fin_b[t * 2 + i - 190];
    }
    const float* wT_g = ws + OFF_WT;
    for (int i4 = tid; i4 < 448; i4 += 256) {
        float4 v = ((const float4*)wT_g)[i4];
        *(float4*)&L[CH + i4 * 4] = v;
    }
    __syncthreads();

    int ng = lane & 15, cg = lane >> 4;
    int c0 = wv * 32 + cg * 8;
    float acc[32];
    #pragma unroll
    for (int i = 0; i < 32; ++i) acc[i] = 0.f;
    int cur = 0;
    for (int q = 0; q < 5; ++q) {
        float4 pf0, pf1;
        if (q < 4) {
            const float4* src = (const float4*)(wT_g + (q + 1) * 1792);
            pf0 = src[tid];
            if (tid < 192) pf1 = src[tid + 256];
        }
        const float* wb = &L[CH + cur * 1792];
        #pragma unroll
        for (int kk = 0; kk < 14; ++kk) {
            float4 a4 = *(const float4*)&L[ST + (q * 14 + kk) * 68 + ng * 4];
            float4 wa = *(const float4*)&wb[kk * 128 + c0];
            float4 wc = *(const float4*)&wb[kk * 128 + c0 + 4];
            float a_[4] = {a4.x, a4.y, a4.z, a4.w};
            float w_[8] = {wa.x, wa.y, wa.z, wa.w, wc.x, wc.y, wc.z, wc.w};
            #pragma unroll
            for (int ni = 0; ni < 4; ++ni)
                #pragma unroll
                for (int ci = 0; ci < 8; ++ci)
                    acc[ni * 8 + ci] += a_[ni] * w_[ci];
        }
        if (q < 4) {
            float* dstb = &L[CH + (cur ^ 1) * 1792];
            *(float4*)&dstb[tid * 4] = pf0;
            if (tid < 192) *(float4*)&dstb[(tid + 256) * 4] = pf1;
        }
        cur ^= 1;
        __syncthreads();
    }

    {
        float4 dv = *(const float4*)&L[SM_DINV + ng * 4];
        float d_[4] = {dv.x, dv.y, dv.z, dv.w};
        #pragma unroll
        for (int ci = 0; ci < 8; ++ci) {
            float cb = L[SM_CB + c0 + ci];
            float4 hv;
            float h0 = acc[0 * 8 + ci] * d_[0] + cb;
            float h1 = acc[1 * 8 + ci] * d_[1] + cb;
            float h2 = acc[2 * 8 + ci] * d_[2] + cb;
            float h3 = acc[3 * 8 + ci] * d_[3] + cb;
            hv.x = h0 > 0.f ? h0 : 0.f;
            hv.y = h1 > 0.f ? h1 : 0.f;
            hv.z = h2 > 0.f ? h2 : 0.f;
            hv.w = h3 > 0.f ? h3 : 0.f;
            *(float4*)&L[HH + (c0 + ci) * 64 + ng * 4] = hv;
        }
    }
    const float* W0g = lin0_W + t * C_DIM * HL_DIM;
    for (int i = tid; i < 608; i += 256) {
        int cc = i / 38, j = i - cc * 38;
        L[CH + cc * 40 + j] = W0g[i];
    }
    __syncthreads();

    int jg = lane >> 4;
    int j0 = wv * 16 + jg * 4;
    float acc2[16];
    #pragma unroll
    for (int i = 0; i < 16; ++i) acc2[i] = 0.f;
    int cur2 = 0;
    for (int q = 0; q < 8; ++q) {
        float pa, pb, pc;
        if (q < 7) {
            const float* src = W0g + (q + 1) * 608;
            pa = src[tid];
            if (tid < 608 - 256) pb = src[tid + 256];
            if (tid < 608 - 512) pc = src[tid + 512];
        }
        const float* wb = &L[CH + cur2 * 1792];
        #pragma unroll
        for (int kk = 0; kk < 16; ++kk) {
            int c = q * 16 + kk;
            float4 a4 = *(const float4*)&L[HH + c * 64 + ng * 4];
            float4 w4 = *(const float4*)&wb[kk * 40 + j0];
            float a_[4] = {a4.x, a4.y, a4.z, a4.w};
            float w_[4] = {w4.x, w4.y, w4.z, w4.w};
            #pragma unroll
            for (int ni = 0; ni < 4; ++ni)
                #pragma unroll
                for (int ji = 0; ji < 4; ++ji)
                    acc2[ni * 4 + ji] += a_[ni] * w_[ji];
        }
        if (q < 7) {
            float* dstb = &L[CH + (cur2 ^ 1) * 1792];
            int i = tid, cc = i / 38, j = i - cc * 38;
            dstb[cc * 40 + j] = pa;
            if (tid < 608 - 256) { i = tid + 256; cc = i / 38; j = i - cc * 38; dstb[cc * 40 + j] = pb; }
            if (tid < 608 - 512) { i = tid + 512; cc = i / 38; j = i - cc * 38; dstb[cc * 40 + j] = pc; }
        }
        cur2 ^= 1;
        __syncthreads();
    }
    #pragma unroll
    for (int ji = 0; ji < 4; ++ji) {
        int j = j0 + ji;
        float b = (j < 38) ? L[SM_B0 + j] : 0.f;
        float4 yv;
        float y0 = acc2[0 * 4 + ji] + b;
        float y1 = acc2[1 * 4 + ji] + b;
        float y2 = acc2[2 * 4 + ji] + b;
        float y3 = acc2[3 * 4 + ji] + b;
        yv.x = y0 > 0.f ? y0 : 0.f;
        yv.y = y1 > 0.f ? y1 : 0.f;
        yv.z = y2 > 0.f ? y2 : 0.f;
        yv.w = y3 > 0.f ? y3 : 0.f;
        *(float4*)&L[ST + j * 68 + ng * 4] = yv;
    }
    {
        const float* W1g = lin1_W + t * HL_DIM * HL_DIM;
        const float* W2g = lin2_W + t * HL_DIM * HL_DIM;
        for (int i = tid; i < 1444; i += 256) {
            int cc = i / 38, j = i - cc * 38;
            L[CH + cc * 40 + j] = W1g[i];
            L[CH + 1520 + cc * 40 + j] = W2g[i];
        }
    }
    __syncthreads();

    float acc3[16];
    #pragma unroll
    for (int i = 0; i < 16; ++i) acc3[i] = 0.f;
    #pragma unroll 2
    for (int kk = 0; kk < 38; ++kk) {
        float4 a4 = *(const float4*)&L[ST + kk * 68 + ng * 4];
        float4 w4 = *(const float4*)&L[CH + kk * 40 + j0];
        float a_[4] = {a4.x, a4.y, a4.z, a4.w};
        float w_[4] = {w4.x, w4.y, w4.z, w4.w};
        #pragma unroll
        for (int ni = 0; ni < 4; ++ni)
            #pragma unroll
            for (int ji = 0; ji < 4; ++ji)
                acc3[ni * 4 + ji] += a_[ni] * w_[ji];
    }
    __syncthreads();
    #pragma unroll
    for (int ji = 0; ji < 4; ++ji) {
        int j = j0 + ji;
        float b = (j < 38) ? L[SM_B1 + j] : 0.f;
        float4 yv;
        float y0 = acc3[0 * 4 + ji] + b;
        float y1 = acc3[1 * 4 + ji] + b;
        float y2 = acc3[2 * 4 + ji] + b;
        float y3 = acc3[3 * 4 + ji] + b;
        yv.x = y0 > 0.f ? y0 : 0.f;
        yv.y = y1 > 0.f ? y1 : 0.f;
        yv.z = y2 > 0.f ? y2 : 0.f;
        yv.w = y3 > 0.f ? y3 : 0.f;
        *(float4*)&L[HH + j * 68 + ng * 4] = yv;
    }
    __syncthreads();

    float acc4[16];
    #pragma unroll
    for (int i = 0; i < 16; ++i) acc4[i] = 0.f;
    #pragma unroll 2
    for (int kk = 0; kk < 38; ++kk) {
        float4 a4 = *(const float4*)&L[HH + kk * 68 + ng * 4];
        float4 w4 = *(const float4*)&L[CH + 1520 + kk * 40 + j0];
        float a_[4] = {a4.x, a4.y, a4.z, a4.w};
        float w_[4] = {w4.x, w4.y, w4.z, w4.w};
        #pragma unroll
        for (int ni = 0; ni < 4; ++ni)
            #pragma unroll
            for (int ji = 0; ji < 4; ++ji)
                acc4[ni * 4 + ji] += a_[ni] * w_[ji];
    }
    #pragma unroll
    for (int ji = 0; ji < 4; ++ji) {
        int j = j0 + ji;
        float b = (j < 38) ? L[SM_B2 + j] : 0.f;
        float4 yv;
        yv.x = acc4[0 * 4 + ji] + b;
        yv.y = acc4[1 * 4 + ji] + b;
        yv.z = acc4[2 * 4 + ji] + b;
        yv.w = acc4[3 * 4 + ji] + b;
        *(float4*)&L[Y2T + j * 68 + ng * 4] = yv;
    }
    __syncthreads();

    if (tid < 64) {
        int p = p0 + tid;
        bool valid = (p - bp) < cnt;
        float o0 = L[SM_FB], o1 = L[SM_FB + 1];
        for (int jj = 0; jj < 38; ++jj) {
            float v = L[Y2T + jj * 68 + tid];
            float2 f = *(const float2*)&L[SM_FW + jj * 2];
            o0 += v * f.x;
            o1 += v * f.y;
        }
        if (t == 0) o1 = fabsf(o1);
        if (valid) {
            int orig = ((const int*)(ws + OFF_INV))[p];
            ((float2*)out)[orig] = make_float2(o0, o1);
        }
    }
}

extern "C" void kernel_launch(void* const* d_in, const int* in_sizes, int n_in,
                              void* d_out, int out_size, void* d_ws, size_t ws_size,
                              hipStream_t stream) {
    const float* x          = (const float*)d_in[0];
    const int*   edge_index = (const int*)  d_in[1];
    const int*   edge_type  = (const int*)  d_in[2];
    const float* edge_attr  = (const float*)d_in[3];
    const int*   node_type  = (const int*)  d_in[4];
    const float* basis      = (const float*)d_in[5];
    const float* att_rel    = (const float*)d_in[6];
    const float* q_att      = (const float*)d_in[7];
    const float* k_att      = (const float*)d_in[8];
    const float* e_att      = (const float*)d_in[9];
    const float* lin_edge_W = (const float*)d_in[10];
    const float* conv_bias  = (const float*)d_in[11];
    const float* lin0_W     = (const float*)d_in[12];
    const float* lin0_b     = (const float*)d_in[13];
    const float* lin1_W     = (const float*)d_in[14];
    const float* lin1_b     = (const float*)d_in[15];
    const float* lin2_W     = (const float*)d_in[16];
    const float* lin2_b     = (const float*)d_in[17];
    const float* fin_W      = (const float*)d_in[18];
    const float* fin_b      = (const float*)d_in[19];

    float* ws  = (float*)d_ws;
    float* out = (float*)d_out;

    k_init   <<<ZERO_BLOCKS + 35, 256, 0, stream>>>(basis, att_rel, ws);
    k_histblk<<<NB_HIST, 256, 0, stream>>>(node_type, ws);
    k_scan   <<<1, 256, 0, stream>>>(ws);
    k_proj   <<<RI2 + 2, 64, 0, stream>>>(q_att, k_att, e_att, lin_edge_W, ws);
    k_perm   <<<NB_HIST, 256, 0, stream>>>(node_type, ws);
    k_edge   <<<(N_EDGES + 255) / 256, 256, 0, stream>>>(x, edge_index, edge_type, edge_attr, ws);
    k_node   <<<NP / 64, 256, 0, stream>>>(ws, conv_bias,
                                           lin0_W, lin0_b, lin1_W, lin1_b,
                                           lin2_W, lin2_b, fin_W, fin_b, out);
}

// Round 7
// 222.021 us; speedup vs baseline: 1.7788x; 1.0324x over previous
//
#include <hip/hip_runtime.h>
#include <math.h>

#define N_NODES 50000
#define N_EDGES 400000
#define R_REL   35
#define B_BASES 12
#define C_DIM   128
#define HL_DIM  38
#define RI2     70
#define NP      50304         // padded permuted node space (mult of 64)
#define NB_HIST 196           // ceil(50000/256)
#define NBUCK   786           // NP/64 — one bucket per k_node tile
#define NBE     98            // edge blocks
#define EPB     4096          // edges per edge-block

// ---- ws float offsets ----
#define OFF_WT     0          // w[ri][c] = [70][128] = 8960
#define OFF_WQ     8960       // [70]
#define OFF_WK     9030       // [70]
#define OFF_LE     9100       // [2]
#define OFF_META   9104       // 16 ints: counts[4]@0, base_pad[4]@4
#define OFF_HBLK   9120       // int[196][4]
#define OFF_BBASE  9904       // int[196][4]
#define OFF_PERM   10688      // int[50000]
#define OFF_INV    60688      // int[NP]
#define OFF_EHIST  110992     // int[98][786]
#define OFF_EBASE  188020     // int[98][786]
#define OFF_ESTART 265048     // int[786]
#define OFF_ECNT   265834     // int[786]
#define OFF_EREC   266624     // float4[400000] (16B aligned: 266624%4==0)

// ---- k_node LDS float offsets ----
#define CH    0
#define ST    3584     // sT[70][68] accumulated from records
#define HH    8344
#define Y2T   11608
#define SM_DINV 16536  // den accumulator -> dinv
#define SM_CB   16600
#define SM_B0   16728
#define SM_B1   16766
#define SM_B2   16804
#define SM_FW   16844
#define SM_FB   16920
#define LDS_FLOATS 16928

// K1: compute w[ri][c] only (no zeroing needed anymore)
__global__ __launch_bounds__(256) void k_init(const float* __restrict__ basis,
                                              const float* __restrict__ att_rel,
                                              float* __restrict__ ws) {
    int idx = blockIdx.x * 256 + threadIdx.x;
    if (idx < RI2 * C_DIM) {
        int c  = idx & (C_DIM - 1);
        int ri = idx >> 7;
        int r = ri >> 1, ii = ri & 1;
        float acc = 0.f;
        #pragma unroll
        for (int bb = 0; bb < B_BASES; ++bb)
            acc += att_rel[r * B_BASES + bb] * basis[(bb * 2 + ii) * C_DIM + c];
        ws[OFF_WT + idx] = acc;
    }
}

// K2: per-block node-type histogram
__global__ __launch_bounds__(256) void k_histblk(const int* __restrict__ node_type,
                                                 float* __restrict__ ws) {
    __shared__ int lh[4];
    int tid = threadIdx.x;
    if (tid < 4) lh[tid] = 0;
    __syncthreads();
    int i = blockIdx.x * 256 + tid;
    if (i < N_NODES) atomicAdd(&lh[node_type[i]], 1);
    __syncthreads();
    if (tid < 4) ((int*)(ws + OFF_HBLK))[blockIdx.x * 4 + tid] = lh[tid];
}

// K3: scan node histograms -> per-block bases + meta
__global__ __launch_bounds__(256) void k_scan(float* __restrict__ ws) {
    __shared__ int lh[NB_HIST * 4];
    __shared__ int basel[4], tot[4];
    int tid = threadIdx.x;
    const int* hblk = (const int*)(ws + OFF_HBLK);
    for (int i = tid; i < NB_HIST * 4; i += 256) lh[i] = hblk[i];
    __syncthreads();
    if (tid < 4) {
        int run = 0;
        for (int b = 0; b < NB_HIST; ++b) {
            int v = lh[b * 4 + tid];
            lh[b * 4 + tid] = run;
            run += v;
        }
        tot[tid] = run;
    }
    __syncthreads();
    if (tid == 0) {
        int* meta = (int*)(ws + OFF_META);
        int t0 = tot[0], t1 = tot[1], t2 = tot[2], t3 = tot[3];
        int b1 = ((t0 + 63) >> 6) << 6;
        int b2 = b1 + (((t1 + 63) >> 6) << 6);
        int b3 = b2 + (((t2 + 63) >> 6) << 6);
        meta[0] = t0; meta[1] = t1; meta[2] = t2; meta[3] = t3;
        meta[4] = 0;  meta[5] = b1; meta[6] = b2; meta[7] = b3;
        basel[0] = 0; basel[1] = b1; basel[2] = b2; basel[3] = b3;
    }
    __syncthreads();
    int* bbase = (int*)(ws + OFF_BBASE);
    for (int i = tid; i < NB_HIST * 4; i += 256) bbase[i] = basel[i & 3] + lh[i];
}

// K4: wq/wk/le projections — one wave each
__global__ __launch_bounds__(64) void k_proj(const float* __restrict__ q_att,
                                             const float* __restrict__ k_att,
                                             const float* __restrict__ e_att,
                                             const float* __restrict__ lin_edge_W,
                                             float* __restrict__ ws) {
    int b = blockIdx.x, l = threadIdx.x;
    if (b < RI2) {
        const float* wr = ws + OFF_WT + b * C_DIM;
        float w1 = wr[l], w2 = wr[64 + l];
        float aq = w1 * q_att[l] + w2 * q_att[64 + l];
        float ak = w1 * k_att[l] + w2 * k_att[64 + l];
        #pragma unroll
        for (int off = 32; off; off >>= 1) {
            aq += __shfl_xor(aq, off, 64);
            ak += __shfl_xor(ak, off, 64);
        }
        if (l == 0) { ws[OFF_WQ + b] = aq; ws[OFF_WK + b] = ak; }
    } else {
        int j = b - RI2;
        const float* er = lin_edge_W + j * C_DIM;
        float a = er[l] * e_att[l] + er[64 + l] * e_att[64 + l];
        #pragma unroll
        for (int off = 32; off; off >>= 1) a += __shfl_xor(a, off, 64);
        if (l == 0) ws[OFF_LE + j] = a;
    }
}

// K5: node permutation — ballots + LDS partials, atomic-free
__global__ __launch_bounds__(256) void k_perm(const int* __restrict__ node_type,
                                              float* __restrict__ ws) {
    __shared__ int wcnt[4][4];
    int tid = threadIdx.x;
    int lane = tid & 63, wv = tid >> 6;
    int n = blockIdx.x * 256 + tid;
    bool active = n < N_NODES;
    int ty = active ? node_type[n] : -1;
    int myrank = 0;
    #pragma unroll
    for (int t = 0; t < 4; ++t) {
        unsigned long long m = __ballot(ty == t);
        if (lane == 0) wcnt[wv][t] = __popcll(m);
        if (ty == t) myrank = __popcll(m & ((1ULL << lane) - 1ULL));
    }
    __syncthreads();
    if (active) {
        int pre = 0;
        for (int w2 = 0; w2 < wv; ++w2) pre += wcnt[w2][ty];
        int p = ((const int*)(ws + OFF_BBASE))[blockIdx.x * 4 + ty] + pre + myrank;
        ((int*)(ws + OFF_PERM))[n] = p;
        ((int*)(ws + OFF_INV))[p] = n;
    }
}

// K6: per-block edge-bucket histogram (bucket = perm[dst] >> 6)
__global__ __launch_bounds__(256) void k_ehist(const int* __restrict__ edge_index,
                                               float* __restrict__ ws) {
    __shared__ int h[NBUCK];
    int tid = threadIdx.x;
    for (int i = tid; i < NBUCK; i += 256) h[i] = 0;
    __syncthreads();
    const int* perm = (const int*)(ws + OFF_PERM);
    int base = blockIdx.x * EPB;
    #pragma unroll
    for (int k = 0; k < 16; ++k) {
        int e = base + k * 256 + tid;
        if (e < N_EDGES) {
            int p = perm[edge_index[N_EDGES + e]];
            atomicAdd(&h[p >> 6], 1);
        }
    }
    __syncthreads();
    int* row = (int*)(ws + OFF_EHIST) + blockIdx.x * NBUCK;
    for (int i = tid; i < NBUCK; i += 256) row[i] = h[i];
}

// K7: scan edge histograms -> segment starts/counts + per-(block,bucket) bases
__global__ __launch_bounds__(1024) void k_escan(float* __restrict__ ws) {
    __shared__ int tot[1024];
    int tid = threadIdx.x;
    const int* eh = (const int*)(ws + OFF_EHIST);
    int* eb = (int*)(ws + OFF_EBASE);
    int total = 0;
    if (tid < NBUCK) {
        for (int b = 0; b < NBE; ++b) {
            eb[b * NBUCK + tid] = total;          // prefix over earlier blocks
            total += eh[b * NBUCK + tid];
        }
    }
    tot[tid] = (tid < NBUCK) ? total : 0;
    __syncthreads();
    for (int off = 1; off < 1024; off <<= 1) {    // Hillis-Steele inclusive scan
        int v = tot[tid];
        int add = (tid >= off) ? tot[tid - off] : 0;
        __syncthreads();
        tot[tid] = v + add;
        __syncthreads();
    }
    if (tid < NBUCK) {
        int start = tot[tid] - total;             // exclusive
        ((int*)(ws + OFF_ESTART))[tid] = start;
        ((int*)(ws + OFF_ECNT))[tid]   = total;
        for (int b = 0; b < NBE; ++b)
            eb[b * NBUCK + tid] += start;
    }
}

// K8: edge scatter — compute ex, write 16B record; NO global atomics
__global__ __launch_bounds__(256) void k_escatter(const float* __restrict__ x,
                                                  const int* __restrict__ edge_index,
                                                  const int* __restrict__ edge_type,
                                                  const float* __restrict__ edge_attr,
                                                  float* __restrict__ ws) {
    __shared__ int cur[NBUCK];
    __shared__ float swq[RI2], swk[RI2], sle[2];
    int tid = threadIdx.x;
    const int* ebase = (const int*)(ws + OFF_EBASE) + blockIdx.x * NBUCK;
    for (int i = tid; i < NBUCK; i += 256) cur[i] = ebase[i];
    if (tid < RI2) { swq[tid] = ws[OFF_WQ + tid]; swk[tid] = ws[OFF_WK + tid]; }
    if (tid < 2) sle[tid] = ws[OFF_LE + tid];
    __syncthreads();
    const int* perm = (const int*)(ws + OFF_PERM);
    float4* rec = (float4*)(ws + OFF_EREC);
    int base = blockIdx.x * EPB;
    #pragma unroll
    for (int k = 0; k < 16; ++k) {
        int e = base + k * 256 + tid;
        if (e >= N_EDGES) continue;
        int src = edge_index[e];
        int dst = edge_index[N_EDGES + e];
        int r   = edge_type[e];
        int p   = perm[dst];
        float2 ea = *(const float2*)(edge_attr + 2 * e);
        float2 xs = *(const float2*)(x + 2 * src);
        float2 xd = *(const float2*)(x + 2 * dst);
        float alpha = xd.x * swq[2 * r] + xd.y * swq[2 * r + 1]
                    + xs.x * swk[2 * r] + xs.y * swk[2 * r + 1]
                    + ea.x * sle[0]     + ea.y * sle[1];
        alpha = alpha > 0.f ? alpha : 0.2f * alpha;
        float ex = __expf(alpha);
        int slot = atomicAdd(&cur[p >> 6], 1);    // LDS atomic only
        rec[slot] = make_float4(__int_as_float((r << 6) | (p & 63)), ex, ex * xs.x, ex * xs.y);
    }
}

// K9: fused node pass — record accumulation in LDS + register-tiled GEMM chain
__global__ __launch_bounds__(256) void k_node(
        const float* __restrict__ ws, const float* __restrict__ conv_bias,
        const float* __restrict__ lin0_W, const float* __restrict__ lin0_b,
        const float* __restrict__ lin1_W, const float* __restrict__ lin1_b,
        const float* __restrict__ lin2_W, const float* __restrict__ lin2_b,
        const float* __restrict__ fin_W,  const float* __restrict__ fin_b,
        float* __restrict__ out) {
    __shared__ float L[LDS_FLOATS];
    int tid  = threadIdx.x;
    int lane = tid & 63;
    int wv   = tid >> 6;
    int p0   = blockIdx.x * 64;

    const int* meta = (const int*)(ws + OFF_META);
    int b1 = meta[5], b2 = meta[6], b3 = meta[7];
    int t  = (p0 >= b1) + (p0 >= b2) + (p0 >= b3);
    int bp = meta[4 + t];
    int cnt = meta[t];

    // ---------- phase 0: zero accumulators, stage consts + wT chunk 0
    for (int i = tid; i < RI2 * 68; i += 256) L[ST + i] = 0.f;
    if (tid < 64) L[SM_DINV + tid] = 0.f;
    if (tid < 128) L[SM_CB + tid] = conv_bias[tid];
    if (tid >= 64 && tid < 256) {
        int i = tid - 64;
        if      (i < 38)  L[SM_B0 + i]        = lin0_b[t * HL_DIM + i];
        else if (i < 76)  L[SM_B1 + i - 38]   = lin1_b[t * HL_DIM + i - 38];
        else if (i < 114) L[SM_B2 + i - 76]   = lin2_b[t * HL_DIM + i - 76];
        else if (i < 190) L[SM_FW + i - 114]  = fin_W[t * 76 + i - 114];
        else              L[SM_FB + i - 190]  = fin_b[t * 2 + i - 190];
    }
    const float* wT_g = ws + OFF_WT;
    for (int i4 = tid; i4 < 448; i4 += 256) {
        float4 v = ((const float4*)wT_g)[i4];
        *(float4*)&L[CH + i4 * 4] = v;
    }
    __syncthreads();

    // ---------- phase 1: accumulate this bucket's edge records (LDS atomics)
    {
        int estart = ((const int*)(ws + OFF_ESTART))[blockIdx.x];
        int ecnt   = ((const int*)(ws + OFF_ECNT))[blockIdx.x];
        const float4* rec = (const float4*)(ws + OFF_EREC) + estart;
        for (int i = tid; i < ecnt; i += 256) {
            float4 v = rec[i];
            int m = __float_as_int(v.x);
            int n = m & 63, r = m >> 6;
            atomicAdd(&L[ST + (2 * r) * 68 + n],     v.z);
            atomicAdd(&L[ST + (2 * r + 1) * 68 + n], v.w);
            atomicAdd(&L[SM_DINV + n],               v.y);
        }
    }
    __syncthreads();
    if (tid < 64) L[SM_DINV + tid] = 1.0f / (L[SM_DINV + tid] + 1e-16f);

    // ---------- GEMM1: H[64n x 128c] = sT x wT
    int ng = lane & 15, cg = lane >> 4;
    int c0 = wv * 32 + cg * 8;
    float acc[32];
    #pragma unroll
    for (int i = 0; i < 32; ++i) acc[i] = 0.f;
    int cur = 0;
    for (int q = 0; q < 5; ++q) {
        float4 pf0, pf1;
        if (q < 4) {
            const float4* src = (const float4*)(wT_g + (q + 1) * 1792);
            pf0 = src[tid];
            if (tid < 192) pf1 = src[tid + 256];
        }
        const float* wb = &L[CH + cur * 1792];
        #pragma unroll
        for (int kk = 0; kk < 14; ++kk) {
            float4 a4 = *(const float4*)&L[ST + (q * 14 + kk) * 68 + ng * 4];
            float4 wa = *(const float4*)&wb[kk * 128 + c0];
            float4 wc = *(const float4*)&wb[kk * 128 + c0 + 4];
            float a_[4] = {a4.x, a4.y, a4.z, a4.w};
            float w_[8] = {wa.x, wa.y, wa.z, wa.w, wc.x, wc.y, wc.z, wc.w};
            #pragma unroll
            for (int ni = 0; ni < 4; ++ni)
                #pragma unroll
                for (int ci = 0; ci < 8; ++ci)
                    acc[ni * 8 + ci] += a_[ni] * w_[ci];
        }
        if (q < 4) {
            float* dstb = &L[CH + (cur ^ 1) * 1792];
            *(float4*)&dstb[tid * 4] = pf0;
            if (tid < 192) *(float4*)&dstb[(tid + 256) * 4] = pf1;
        }
        cur ^= 1;
        __syncthreads();
    }

    // epilogue 1
    {
        float4 dv = *(const float4*)&L[SM_DINV + ng * 4];
        float d_[4] = {dv.x, dv.y, dv.z, dv.w};
        #pragma unroll
        for (int ci = 0; ci < 8; ++ci) {
            float cb = L[SM_CB + c0 + ci];
            float4 hv;
            float h0 = acc[0 * 8 + ci] * d_[0] + cb;
            float h1 = acc[1 * 8 + ci] * d_[1] + cb;
            float h2 = acc[2 * 8 + ci] * d_[2] + cb;
            float h3 = acc[3 * 8 + ci] * d_[3] + cb;
            hv.x = h0 > 0.f ? h0 : 0.f;
            hv.y = h1 > 0.f ? h1 : 0.f;
            hv.z = h2 > 0.f ? h2 : 0.f;
            hv.w = h3 > 0.f ? h3 : 0.f;
            *(float4*)&L[HH + (c0 + ci) * 64 + ng * 4] = hv;
        }
    }
    const float* W0g = lin0_W + t * C_DIM * HL_DIM;
    for (int i = tid; i < 608; i += 256) {
        int cc = i / 38, j = i - cc * 38;
        L[CH + cc * 40 + j] = W0g[i];
    }
    __syncthreads();

    // ---------- GEMM2: y0 = H x W0
    int jg = lane >> 4;
    int j0 = wv * 16 + jg * 4;
    float acc2[16];
    #pragma unroll
    for (int i = 0; i < 16; ++i) acc2[i] = 0.f;
    int cur2 = 0;
    for (int q = 0; q < 8; ++q) {
        float pa, pb, pc;
        if (q < 7) {
            const float* src = W0g + (q + 1) * 608;
            pa = src[tid];
            if (tid < 608 - 256) pb = src[tid + 256];
            if (tid < 608 - 512) pc = src[tid + 512];
        }
        const float* wb = &L[CH + cur2 * 1792];
        #pragma unroll
        for (int kk = 0; kk < 16; ++kk) {
            int c = q * 16 + kk;
            float4 a4 = *(const float4*)&L[HH + c * 64 + ng * 4];
            float4 w4 = *(const float4*)&wb[kk * 40 + j0];
            float a_[4] = {a4.x, a4.y, a4.z, a4.w};
            float w_[4] = {w4.x, w4.y, w4.z, w4.w};
            #pragma unroll
            for (int ni = 0; ni < 4; ++ni)
                #pragma unroll
                for (int ji = 0; ji < 4; ++ji)
                    acc2[ni * 4 + ji] += a_[ni] * w_[ji];
        }
        if (q < 7) {
            float* dstb = &L[CH + (cur2 ^ 1) * 1792];
            int i = tid, cc = i / 38, j = i - cc * 38;
            dstb[cc * 40 + j] = pa;
            if (tid < 608 - 256) { i = tid + 256; cc = i / 38; j = i - cc * 38; dstb[cc * 40 + j] = pb; }
            if (tid < 608 - 512) { i = tid + 512; cc = i / 38; j = i - cc * 38; dstb[cc * 40 + j] = pc; }
        }
        cur2 ^= 1;
        __syncthreads();
    }
    #pragma unroll
    for (int ji = 0; ji < 4; ++ji) {
        int j = j0 + ji;
        float b = (j < 38) ? L[SM_B0 + j] : 0.f;
        float4 yv;
        float y0 = acc2[0 * 4 + ji] + b;
        float y1 = acc2[1 * 4 + ji] + b;
        float y2 = acc2[2 * 4 + ji] + b;
        float y3 = acc2[3 * 4 + ji] + b;
        yv.x = y0 > 0.f ? y0 : 0.f;
        yv.y = y1 > 0.f ? y1 : 0.f;
        yv.z = y2 > 0.f ? y2 : 0.f;
        yv.w = y3 > 0.f ? y3 : 0.f;
        *(float4*)&L[ST + j * 68 + ng * 4] = yv;
    }
    {
        const float* W1g = lin1_W + t * HL_DIM * HL_DIM;
        const float* W2g = lin2_W + t * HL_DIM * HL_DIM;
        for (int i = tid; i < 1444; i += 256) {
            int cc = i / 38, j = i - cc * 38;
            L[CH + cc * 40 + j] = W1g[i];
            L[CH + 1520 + cc * 40 + j] = W2g[i];
        }
    }
    __syncthreads();

    // ---------- GEMM3
    float acc3[16];
    #pragma unroll
    for (int i = 0; i < 16; ++i) acc3[i] = 0.f;
    #pragma unroll 2
    for (int kk = 0; kk < 38; ++kk) {
        float4 a4 = *(const float4*)&L[ST + kk * 68 + ng * 4];
        float4 w4 = *(const float4*)&L[CH + kk * 40 + j0];
        float a_[4] = {a4.x, a4.y, a4.z, a4.w};
        float w_[4] = {w4.x, w4.y, w4.z, w4.w};
        #pragma unroll
        for (int ni = 0; ni < 4; ++ni)
            #pragma unroll
            for (int ji = 0; ji < 4; ++ji)
                acc3[ni * 4 + ji] += a_[ni] * w_[ji];
    }
    __syncthreads();
    #pragma unroll
    for (int ji = 0; ji < 4; ++ji) {
        int j = j0 + ji;
        float b = (j < 38) ? L[SM_B1 + j] : 0.f;
        float4 yv;
        float y0 = acc3[0 * 4 + ji] + b;
        float y1 = acc3[1 * 4 + ji] + b;
        float y2 = acc3[2 * 4 + ji] + b;
        float y3 = acc3[3 * 4 + ji] + b;
        yv.x = y0 > 0.f ? y0 : 0.f;
        yv.y = y1 > 0.f ? y1 : 0.f;
        yv.z = y2 > 0.f ? y2 : 0.f;
        yv.w = y3 > 0.f ? y3 : 0.f;
        *(float4*)&L[HH + j * 68 + ng * 4] = yv;
    }
    __syncthreads();

    // ---------- GEMM4
    float acc4[16];
    #pragma unroll
    for (int i = 0; i < 16; ++i) acc4[i] = 0.f;
    #pragma unroll 2
    for (int kk = 0; kk < 38; ++kk) {
        float4 a4 = *(const float4*)&L[HH + kk * 68 + ng * 4];
        float4 w4 = *(const float4*)&L[CH + 1520 + kk * 40 + j0];
        float a_[4] = {a4.x, a4.y, a4.z, a4.w};
        float w_[4] = {w4.x, w4.y, w4.z, w4.w};
        #pragma unroll
        for (int ni = 0; ni < 4; ++ni)
            #pragma unroll
            for (int ji = 0; ji < 4; ++ji)
                acc4[ni * 4 + ji] += a_[ni] * w_[ji];
    }
    #pragma unroll
    for (int ji = 0; ji < 4; ++ji) {
        int j = j0 + ji;
        float b = (j < 38) ? L[SM_B2 + j] : 0.f;
        float4 yv;
        yv.x = acc4[0 * 4 + ji] + b;
        yv.y = acc4[1 * 4 + ji] + b;
        yv.z = acc4[2 * 4 + ji] + b;
        yv.w = acc4[3 * 4 + ji] + b;
        *(float4*)&L[Y2T + j * 68 + ng * 4] = yv;
    }
    __syncthreads();

    // ---------- final: fin [38]->[2]
    if (tid < 64) {
        int p = p0 + tid;
        bool valid = (p - bp) < cnt;
        float o0 = L[SM_FB], o1 = L[SM_FB + 1];
        for (int jj = 0; jj < 38; ++jj) {
            float v = L[Y2T + jj * 68 + tid];
            float2 f = *(const float2*)&L[SM_FW + jj * 2];
            o0 += v * f.x;
            o1 += v * f.y;
        }
        if (t == 0) o1 = fabsf(o1);
        if (valid) {
            int orig = ((const int*)(ws + OFF_INV))[p];
            ((float2*)out)[orig] = make_float2(o0, o1);
        }
    }
}

extern "C" void kernel_launch(void* const* d_in, const int* in_sizes, int n_in,
                              void* d_out, int out_size, void* d_ws, size_t ws_size,
                              hipStream_t stream) {
    const float* x          = (const float*)d_in[0];
    const int*   edge_index = (const int*)  d_in[1];
    const int*   edge_type  = (const int*)  d_in[2];
    const float* edge_attr  = (const float*)d_in[3];
    const int*   node_type  = (const int*)  d_in[4];
    const float* basis      = (const float*)d_in[5];
    const float* att_rel    = (const float*)d_in[6];
    const float* q_att      = (const float*)d_in[7];
    const float* k_att      = (const float*)d_in[8];
    const float* e_att      = (const float*)d_in[9];
    const float* lin_edge_W = (const float*)d_in[10];
    const float* conv_bias  = (const float*)d_in[11];
    const float* lin0_W     = (const float*)d_in[12];
    const float* lin0_b     = (const float*)d_in[13];
    const float* lin1_W     = (const float*)d_in[14];
    const float* lin1_b     = (const float*)d_in[15];
    const float* lin2_W     = (const float*)d_in[16];
    const float* lin2_b     = (const float*)d_in[17];
    const float* fin_W      = (const float*)d_in[18];
    const float* fin_b      = (const float*)d_in[19];

    float* ws  = (float*)d_ws;
    float* out = (float*)d_out;

    k_init    <<<35, 256, 0, stream>>>(basis, att_rel, ws);
    k_histblk <<<NB_HIST, 256, 0, stream>>>(node_type, ws);
    k_scan    <<<1, 256, 0, stream>>>(ws);
    k_proj    <<<RI2 + 2, 64, 0, stream>>>(q_att, k_att, e_att, lin_edge_W, ws);
    k_perm    <<<NB_HIST, 256, 0, stream>>>(node_type, ws);
    k_ehist   <<<NBE, 256, 0, stream>>>(edge_index, ws);
    k_escan   <<<1, 1024, 0, stream>>>(ws);
    k_escatter<<<NBE, 256, 0, stream>>>(x, edge_index, edge_type, edge_attr, ws);
    k_node    <<<NBUCK, 256, 0, stream>>>(ws, conv_bias,
                                          lin0_W, lin0_b, lin1_W, lin1_b,
                                          lin2_W, lin2_b, fin_W, fin_b, out);
}